// Round 10
// baseline (2577.201 us; speedup 1.0000x reference)
//
#include <hip/hip_runtime.h>
#include <hip/hip_bf16.h>

// ---------------------------------------------------------------------------
// Fused 2-layer GRU + ReLU + Linear, SPLIT into two sequential kernels.
// Root cause found in R1-R9: unified RF = 512 regs/SIMD (arch+acc); compiler
// splits 50/50 when AGPRs are in use, so any per-thread weight set bigger than
// the arch half lives in AGPRs and pays a v_accvgpr_read per (single-use) dot2
// -- a ~2x VALU tax unmovable by launch_bounds/waves_per_eu/LDS pads/asm "v".
// Fix: cut per-kernel demand below the arch half. W_ih1 @ h1_t is NOT
// recurrent once h1 is materialized, so:
//   K1: layer-1 recurrence only (wi0+wh0 = 30 h2/thread @1024 thr), h1 -> ws
//   K2: layer-2 + ReLU + Linear (wi1+wh1 = 48 h2/thread), h1 read back
// Both: octet (8 lanes) owns rows {o,128+o,256+o}, k-split x8; gate partials
// reduced by shfl_xor butterfly (no LDS round trip); E runs in ko==0 lanes
// with h_prev register-resident; state double-buffered in LDS -> ONE barrier
// per step (was 2).
// ---------------------------------------------------------------------------

typedef _Float16 h2 __attribute__((ext_vector_type(2)));

#if __has_builtin(__builtin_amdgcn_fdot2)
__device__ __forceinline__ float dot2f(h2 a, h2 b, float c) {
  return __builtin_amdgcn_fdot2(a, b, c, false);
}
#else
__device__ __forceinline__ float dot2f(h2 a, h2 b, float c) {
  return c + (float)a[0] * (float)b[0] + (float)a[1] * (float)b[1];
}
#endif

__device__ __forceinline__ h2 pack2(float x, float y) {
  h2 r; r[0] = (_Float16)x; r[1] = (_Float16)y; return r;
}
__device__ __forceinline__ float sigm(float x) {
  return 1.0f / (1.0f + __expf(-x));
}
__device__ __forceinline__ float tanh_f(float x) {
  x = fminf(fmaxf(x, -15.f), 15.f);
  float e = __expf(2.f * x);
  return (e - 1.f) / (e + 1.f);
}
__device__ __forceinline__ void load_pack8(const float* p, h2* w) {
  float4 a = ((const float4*)p)[0], b = ((const float4*)p)[1];
  w[0] = pack2(a.x, a.y); w[1] = pack2(a.z, a.w);
  w[2] = pack2(b.x, b.y); w[3] = pack2(b.z, b.w);
}

#define SEQ 1200
#define HID 128
#define INSZ 32

#define DOT4Q(W, F, ACC)                                                \
  ACC = dot2f((W)[0], __builtin_bit_cast(h2, (F).x), ACC);              \
  ACC = dot2f((W)[1], __builtin_bit_cast(h2, (F).y), ACC);              \
  ACC = dot2f((W)[2], __builtin_bit_cast(h2, (F).z), ACC);              \
  ACC = dot2f((W)[3], __builtin_bit_cast(h2, (F).w), ACC);

#define DOT8(W, FA, FB, ACC)                                            \
  DOT4Q(&(W)[0], FA, ACC) DOT4Q(&(W)[4], FB, ACC)

#define RED8(A) \
  A += __shfl_xor(A, 1, 64); A += __shfl_xor(A, 2, 64); A += __shfl_xor(A, 4, 64);

// =================== Kernel 1: layer-1 GRU, h1 -> scratch ===================
__global__ __launch_bounds__(1024) void gru_l1(
    const float* __restrict__ x,
    const float* __restrict__ Wih0, const float* __restrict__ Whh0,
    const float* __restrict__ bih0, const float* __restrict__ bhh0,
    unsigned short* __restrict__ h1g)
{
  const int tid = threadIdx.x;
  const int b   = blockIdx.x;
  const int o   = tid >> 3;   // row-triplet 0..127 -> rows {o, 128+o, 256+o}
  const int ko  = tid & 7;    // k-eighth

  __shared__ _Float16 s0h[2][HID];   // h1 state, f16, double-buffered
  __shared__ _Float16 xh[2][INSZ];   // packed x row, double-buffered

  // per-thread weights: 30 h2 (fits the 64-reg arch half at 4 waves/SIMD)
  h2 wi0[3][2];   // W_ih0 rows, k-eighth (4 elems)
  h2 wh0[3][8];   // W_hh0 rows, k-eighth (16 elems)
#pragma unroll
  for (int rr = 0; rr < 3; ++rr) {
    const int row = rr * HID + o;
    float4 v = *(const float4*)(Wih0 + (size_t)row * INSZ + ko * 4);
    wi0[rr][0] = pack2(v.x, v.y); wi0[rr][1] = pack2(v.z, v.w);
    load_pack8(Whh0 + (size_t)row * HID + ko * 16,     &wh0[rr][0]);
    load_pack8(Whh0 + (size_t)row * HID + ko * 16 + 8, &wh0[rr][4]);
  }
  const float bA = bih0[o] + bhh0[o];
  const float bB = bih0[HID + o] + bhh0[HID + o];
  const float bC = bih0[2 * HID + o];
  const float bD = bhh0[2 * HID + o];

  float hprev = 0.f;
  if (tid < 64) ((float*)s0h[0])[tid] = 0.f;  // 128 f16 zeros
  const float2* xsrc = (const float2*)x + (size_t)b * SEQ * (INSZ / 2);
  if (tid < 16) { float2 v = xsrc[tid]; ((h2*)xh[0])[tid] = pack2(v.x, v.y); }
  __syncthreads();

  unsigned short* hout = h1g + (size_t)b * SEQ * HID;

  for (int t = 0; t < SEQ; ++t) {
    const int rb = t & 1, wb = rb ^ 1;
    // prefetch x_{t+1} (16 loader threads, ko==1 so they never collide with E)
    float2 xn;
    const bool ldx = (ko == 1) && (o < 16);
    if (ldx) xn = xsrc[(size_t)((t + 1 < SEQ) ? t + 1 : SEQ - 1) * 16 + o];

    const float2 xv = ((const float2*)xh[rb])[ko];
    const h2 x0 = __builtin_bit_cast(h2, xv.x);
    const h2 x1 = __builtin_bit_cast(h2, xv.y);
    const float4 sA = ((const float4*)s0h[rb])[ko * 2];
    const float4 sB = ((const float4*)s0h[rb])[ko * 2 + 1];

    float a0 = 0.f, a1 = 0.f, a2 = 0.f, a3 = 0.f;
    a0 = dot2f(wi0[0][0], x0, a0); a0 = dot2f(wi0[0][1], x1, a0);
    DOT8(wh0[0], sA, sB, a0)                       // r: x-part + h-part
    a1 = dot2f(wi0[1][0], x0, a1); a1 = dot2f(wi0[1][1], x1, a1);
    DOT8(wh0[1], sA, sB, a1)                       // z
    a2 = dot2f(wi0[2][0], x0, a2); a2 = dot2f(wi0[2][1], x1, a2);  // n, x-part
    DOT8(wh0[2], sA, sB, a3)                       // n, h-part
    RED8(a0) RED8(a1) RED8(a2) RED8(a3)            // octet butterfly reduce

    if (ko == 0) {
      float r = sigm(a0 + bA);
      float z = sigm(a1 + bB);
      float n = tanh_f(a2 + bC + r * (a3 + bD));
      float h = (1.f - z) * n + z * hprev;
      hprev = h;
      const _Float16 hf = (_Float16)h;
      s0h[wb][o] = hf;
      hout[(size_t)t * HID + o] = __builtin_bit_cast(unsigned short, hf);
    } else if (ldx) {
      ((h2*)xh[wb])[o] = pack2(xn.x, xn.y);
    }
    __syncthreads();
  }
}

// ============ Kernel 2: layer-2 GRU + ReLU + Linear head -> out ============
__global__ __launch_bounds__(1024) void gru_l2(
    const unsigned short* __restrict__ h1g,
    const float* __restrict__ Wih1, const float* __restrict__ Whh1,
    const float* __restrict__ bih1, const float* __restrict__ bhh1,
    const float* __restrict__ Wlin, const float* __restrict__ blin,
    float* __restrict__ out)
{
  const int tid = threadIdx.x;
  const int b   = blockIdx.x;
  const int o   = tid >> 3;
  const int ko  = tid & 7;

  __shared__ _Float16 s1h[2][HID];   // h2 state, double-buffered
  __shared__ _Float16 hb[2][HID];    // staged h1_t, double-buffered
  __shared__ float    pbf[2][16];    // output partials per wave, double-buffered

  // per-thread weights: 48 h2
  h2 wi1[3][8];   // W_ih1 rows, k-eighth (16 elems)
  h2 wh1[3][8];   // W_hh1 rows, k-eighth
#pragma unroll
  for (int rr = 0; rr < 3; ++rr) {
    const int row = rr * HID + o;
    load_pack8(Wih1 + (size_t)row * HID + ko * 16,     &wi1[rr][0]);
    load_pack8(Wih1 + (size_t)row * HID + ko * 16 + 8, &wi1[rr][4]);
    load_pack8(Whh1 + (size_t)row * HID + ko * 16,     &wh1[rr][0]);
    load_pack8(Whh1 + (size_t)row * HID + ko * 16 + 8, &wh1[rr][4]);
  }
  const float bA = bih1[o] + bhh1[o];
  const float bB = bih1[HID + o] + bhh1[HID + o];
  const float bC = bih1[2 * HID + o];
  const float bD = bhh1[2 * HID + o];
  const float wl  = Wlin[o];
  const float blv = blin[0];

  float hprev = 0.f;
  if (tid < 64) ((float*)s1h[0])[tid] = 0.f;
  const uint4* hsrc = (const uint4*)(h1g + (size_t)b * SEQ * HID);  // 16 uint4/t
  if (tid < 16) ((uint4*)hb[0])[tid] = hsrc[tid];
  __syncthreads();

  float* outp = out + (size_t)b * SEQ;

  for (int t = 0; t < SEQ; ++t) {
    const int rb = t & 1, wb = rb ^ 1;
    // prefetch h1_{t+1}
    uint4 hn;
    const bool ldh = (ko == 1) && (o < 16);
    if (ldh) hn = hsrc[(size_t)((t + 1 < SEQ) ? t + 1 : SEQ - 1) * 16 + o];

    const float4 hA = ((const float4*)hb[rb])[ko * 2];
    const float4 hB = ((const float4*)hb[rb])[ko * 2 + 1];
    const float4 sA = ((const float4*)s1h[rb])[ko * 2];
    const float4 sB = ((const float4*)s1h[rb])[ko * 2 + 1];

    float a0 = 0.f, a1 = 0.f, a2 = 0.f, a3 = 0.f;
    DOT8(wi1[0], hA, hB, a0) DOT8(wh1[0], sA, sB, a0)   // r
    DOT8(wi1[1], hA, hB, a1) DOT8(wh1[1], sA, sB, a1)   // z
    DOT8(wi1[2], hA, hB, a2)                             // n, x-part
    DOT8(wh1[2], sA, sB, a3)                             // n, h-part
    RED8(a0) RED8(a1) RED8(a2) RED8(a3)

    float p = 0.f;
    if (ko == 0) {
      float r = sigm(a0 + bA);
      float z = sigm(a1 + bB);
      float n = tanh_f(a2 + bC + r * (a3 + bD));
      float h = (1.f - z) * n + z * hprev;
      hprev = h;
      s1h[wb][o] = (_Float16)h;
      p = fmaxf(h, 0.f) * wl;
    } else if (ldh) {
      ((uint4*)hb[wb])[o] = hn;
    }
    // wave-sum of the 8 octet contributions (lanes ko==0; others add zeros)
    p += __shfl_xor(p, 8, 64);
    p += __shfl_xor(p, 16, 64);
    p += __shfl_xor(p, 32, 64);
    if ((tid & 63) == 0) pbf[rb][tid >> 6] = p;
    if (tid == 2 && t >= 1) {   // store out[t-1] from previous step's partials
      float s = 0.f;
#pragma unroll
      for (int j = 0; j < 16; ++j) s += pbf[wb][j];
      outp[t - 1] = s + blv;
    }
    __syncthreads();
  }

  if (tid == 2) {
    float s = 0.f;
#pragma unroll
    for (int j = 0; j < 16; ++j) s += pbf[(SEQ - 1) & 1][j];
    outp[SEQ - 1] = s + blv;
  }
}

extern "C" void kernel_launch(void* const* d_in, const int* in_sizes, int n_in,
                              void* d_out, int out_size, void* d_ws, size_t ws_size,
                              hipStream_t stream) {
  const float* x    = (const float*)d_in[0];
  const float* Wih0 = (const float*)d_in[1];
  const float* Whh0 = (const float*)d_in[2];
  const float* bih0 = (const float*)d_in[3];
  const float* bhh0 = (const float*)d_in[4];
  const float* Wih1 = (const float*)d_in[5];
  const float* Whh1 = (const float*)d_in[6];
  const float* bih1 = (const float*)d_in[7];
  const float* bhh1 = (const float*)d_in[8];
  const float* Wlin = (const float*)d_in[9];
  const float* blin = (const float*)d_in[10];
  float* outp = (float*)d_out;

  const int Bn = in_sizes[0] / (SEQ * INSZ);   // 256
  unsigned short* h1g = (unsigned short*)d_ws; // B*SEQ*HID f16 = 78.6 MB

  hipLaunchKernelGGL(gru_l1, dim3(Bn), dim3(1024), 0, stream,
                     x, Wih0, Whh0, bih0, bhh0, h1g);
  hipLaunchKernelGGL(gru_l2, dim3(Bn), dim3(1024), 0, stream,
                     h1g, Wih1, Whh1, bih1, bhh1, Wlin, blin, outp);
}

// Round 11
// 2095.006 us; speedup vs baseline: 1.2302x; 1.2302x over previous
//
#include <hip/hip_runtime.h>
#include <hip/hip_bf16.h>

// ---------------------------------------------------------------------------
// 2-layer GRU + ReLU + Linear as two sequential kernels (256 blocks x 512 thr).
// Empirical allocator law from R1-R10: arch-VGPR budget = 65536/blockDim
// (targets 2 blocks/CU); weights beyond it live in AGPRs at ~6cyc/dot2 tax.
// So each kernel keeps register demand < 128 @ 512 threads:
//   K1: wi0(12)+wh0(48) h2 in regs                         -> ~112 demand
//   K2: wi1 r,z (32) in regs; wh1 r,z,n + wi1 n (64 h2) streamed from LDS
//       (128KB, wlds[chunk][tid] b128 conflict-free)       -> ~115 demand
// Second fix: __syncthreads drains vmcnt(0) -> every-step global stores cost
// ~600-900cyc (R10's K1). Use light barriers (lgkmcnt-only s_barrier) and
// batch h1/out stores x16 through double-buffered LDS rings.
// Structure per step: octet... quad (4 lanes) owns units {q,128+q,256+q};
// butterfly shfl reduce; E in ql==0 lanes; state double-buffered -> 1 barrier.
// ---------------------------------------------------------------------------

typedef _Float16 h2 __attribute__((ext_vector_type(2)));

__device__ __forceinline__ float dot2f(h2 a, h2 b, float c) {
#if __has_builtin(__builtin_amdgcn_fdot2)
  return __builtin_amdgcn_fdot2(a, b, c, false);
#else
  return c + (float)a[0] * (float)b[0] + (float)a[1] * (float)b[1];
#endif
}
__device__ __forceinline__ h2 pack2(float x, float y) {
  h2 r; r[0] = (_Float16)x; r[1] = (_Float16)y; return r;
}
__device__ __forceinline__ float sigm(float x) { return 1.f / (1.f + __expf(-x)); }
__device__ __forceinline__ float tanh_f(float x) {
  x = fminf(fmaxf(x, -15.f), 15.f);
  float e = __expf(2.f * x);
  return (e - 1.f) / (e + 1.f);
}
__device__ __forceinline__ void load_pack8(const float* p, h2* w) {
  float4 a = ((const float4*)p)[0], b = ((const float4*)p)[1];
  w[0] = pack2(a.x, a.y); w[1] = pack2(a.z, a.w);
  w[2] = pack2(b.x, b.y); w[3] = pack2(b.z, b.w);
}
__device__ __forceinline__ uint4 pack8u(const float* p) {
  float4 a = ((const float4*)p)[0], b = ((const float4*)p)[1];
  uint4 u;
  u.x = __builtin_bit_cast(unsigned, pack2(a.x, a.y));
  u.y = __builtin_bit_cast(unsigned, pack2(a.z, a.w));
  u.z = __builtin_bit_cast(unsigned, pack2(b.x, b.y));
  u.w = __builtin_bit_cast(unsigned, pack2(b.z, b.w));
  return u;
}
// Light barrier: waits LDS ops only (no vmcnt drain -> global stores float).
__device__ __forceinline__ void lbar() {
  asm volatile("s_waitcnt lgkmcnt(0)\ns_barrier" ::: "memory");
}

#define SEQ 1200
#define HID 128
#define INSZ 32

// dot a 4-h2 weight group (h2*) against a uint4 state fragment (8 f16)
#define DOTU4(W, U, ACC)                                            \
  ACC = dot2f((W)[0], __builtin_bit_cast(h2, (U).x), ACC);          \
  ACC = dot2f((W)[1], __builtin_bit_cast(h2, (U).y), ACC);          \
  ACC = dot2f((W)[2], __builtin_bit_cast(h2, (U).z), ACC);          \
  ACC = dot2f((W)[3], __builtin_bit_cast(h2, (U).w), ACC);
// dot a uint4 of weights against a uint4 of state
#define DOTW(WU, SU, ACC)                                                              \
  ACC = dot2f(__builtin_bit_cast(h2, (WU).x), __builtin_bit_cast(h2, (SU).x), ACC);    \
  ACC = dot2f(__builtin_bit_cast(h2, (WU).y), __builtin_bit_cast(h2, (SU).y), ACC);    \
  ACC = dot2f(__builtin_bit_cast(h2, (WU).z), __builtin_bit_cast(h2, (SU).z), ACC);    \
  ACC = dot2f(__builtin_bit_cast(h2, (WU).w), __builtin_bit_cast(h2, (SU).w), ACC);

// =================== Kernel 1: layer-1 GRU, h1 -> scratch ===================
__global__ __launch_bounds__(512) void gru_l1(
    const float* __restrict__ x,
    const float* __restrict__ Wih0, const float* __restrict__ Whh0,
    const float* __restrict__ bih0, const float* __restrict__ bhh0,
    unsigned short* __restrict__ h1g)
{
  const int tid = threadIdx.x, b = blockIdx.x;
  const int q = tid >> 2, ql = tid & 3;   // unit q, k-quarter ql

  __shared__ __align__(16) _Float16 s0h[2][HID];        // h1 state, dbl-buf
  __shared__ __align__(16) _Float16 xh[2][INSZ];        // x row, dbl-buf
  __shared__ __align__(16) _Float16 ring[2][16][HID];   // h1 out ring (8KB)

  h2 wi0[3][4], wh0[3][16];   // 60 h2 regs
#pragma unroll
  for (int rr = 0; rr < 3; ++rr) {
    const int row = rr * HID + q;
    load_pack8(Wih0 + (size_t)row * INSZ + ql * 8, wi0[rr]);
#pragma unroll
    for (int c = 0; c < 4; ++c)
      load_pack8(Whh0 + (size_t)row * HID + ql * 32 + c * 8, &wh0[rr][c * 4]);
  }
  const float bA = bih0[q] + bhh0[q];
  const float bB = bih0[HID + q] + bhh0[HID + q];
  const float bC = bih0[2 * HID + q];
  const float bD = bhh0[2 * HID + q];

  float hprev = 0.f;
  if (tid < 64) ((float*)s0h[0])[tid] = 0.f;
  const float2* xsrc = (const float2*)x + (size_t)b * SEQ * (INSZ / 2);
  if (tid < 16) { float2 v = xsrc[tid]; ((h2*)xh[0])[tid] = pack2(v.x, v.y); }
  __syncthreads();

  unsigned short* hout = h1g + (size_t)b * SEQ * HID;

  for (int t = 0; t < SEQ; ++t) {
    const int rb = t & 1, wb = rb ^ 1;
    const bool ldx = (ql == 2) && (q < 16);
    float2 xn;
    if (ldx) xn = xsrc[(size_t)((t + 1 < SEQ) ? t + 1 : SEQ - 1) * 16 + q];

    const uint4 xq = ((const uint4*)xh[rb])[ql];
    const uint4* sp = (const uint4*)s0h[rb];
    const uint4 s0 = sp[ql * 4], s1 = sp[ql * 4 + 1],
                s2 = sp[ql * 4 + 2], s3 = sp[ql * 4 + 3];

    float a0 = 0.f, a0b = 0.f, a1 = 0.f, a1b = 0.f, a2 = 0.f, a3 = 0.f, a3b = 0.f;
    DOTU4(wi0[0], xq, a0)
    DOTU4(&wh0[0][0], s0, a0)  DOTU4(&wh0[0][4], s1, a0)
    DOTU4(&wh0[0][8], s2, a0b) DOTU4(&wh0[0][12], s3, a0b)
    DOTU4(wi0[1], xq, a1)
    DOTU4(&wh0[1][0], s0, a1)  DOTU4(&wh0[1][4], s1, a1)
    DOTU4(&wh0[1][8], s2, a1b) DOTU4(&wh0[1][12], s3, a1b)
    DOTU4(wi0[2], xq, a2)
    DOTU4(&wh0[2][0], s0, a3)  DOTU4(&wh0[2][4], s1, a3)
    DOTU4(&wh0[2][8], s2, a3b) DOTU4(&wh0[2][12], s3, a3b)
    a0 += a0b; a1 += a1b; a3 += a3b;
    a0 += __shfl_xor(a0, 1, 64); a0 += __shfl_xor(a0, 2, 64);
    a1 += __shfl_xor(a1, 1, 64); a1 += __shfl_xor(a1, 2, 64);
    a2 += __shfl_xor(a2, 1, 64); a2 += __shfl_xor(a2, 2, 64);
    a3 += __shfl_xor(a3, 1, 64); a3 += __shfl_xor(a3, 2, 64);

    if (ql == 0) {
      float r = sigm(a0 + bA);
      float z = sigm(a1 + bB);
      float n = tanh_f(a2 + bC + r * (a3 + bD));
      float h = (1.f - z) * n + z * hprev;
      hprev = h;
      const _Float16 hf = (_Float16)h;
      s0h[wb][q] = hf;
      ring[(t >> 4) & 1][t & 15][q] = hf;
    } else if (ldx) {
      ((h2*)xh[wb])[q] = pack2(xn.x, xn.y);
    }
    lbar();
    if ((t & 15) == 15) {   // flush 16 rows (4KB) coalesced; drains lazily
      const uint2 v = ((const uint2*)ring[(t >> 4) & 1])[tid];
      ((uint2*)(hout + (size_t)(t - 15) * HID))[tid] = v;
    }
  }
}

// ============ Kernel 2: layer-2 GRU + ReLU + Linear head -> out ============
__global__ __launch_bounds__(512) void gru_l2(
    const unsigned short* __restrict__ h1g,
    const float* __restrict__ Wih1, const float* __restrict__ Whh1,
    const float* __restrict__ bih1, const float* __restrict__ bhh1,
    const float* __restrict__ Wlin, const float* __restrict__ blin,
    float* __restrict__ out)
{
  const int tid = threadIdx.x, b = blockIdx.x;
  const int q = tid >> 2, ql = tid & 3;

  __shared__ __align__(16) _Float16 s1h[2][HID];   // h2 state, dbl-buf
  __shared__ __align__(16) _Float16 hb[2][HID];    // staged h1_t, dbl-buf
  __shared__ uint4 wlds[16][512];                  // 128KB streamed weights
  __shared__ float pw[2][8];                       // per-wave out partials
  __shared__ float obuf[2][16];                    // out ring

  // regs: wi1 r,z rows (32 h2). LDS: wh1 r(0-3), wh1 z(4-7), wi1 n(8-11),
  // wh1 n(12-15) — each 4 chunks of 4 h2.
  h2 wi1r[16], wi1z[16];
  {
    const int rowr = q, rowz = HID + q, rown = 2 * HID + q;
#pragma unroll
    for (int c = 0; c < 4; ++c) {
      load_pack8(Wih1 + (size_t)rowr * HID + ql * 32 + c * 8, &wi1r[c * 4]);
      load_pack8(Wih1 + (size_t)rowz * HID + ql * 32 + c * 8, &wi1z[c * 4]);
      wlds[c][tid]      = pack8u(Whh1 + (size_t)rowr * HID + ql * 32 + c * 8);
      wlds[4 + c][tid]  = pack8u(Whh1 + (size_t)rowz * HID + ql * 32 + c * 8);
      wlds[8 + c][tid]  = pack8u(Wih1 + (size_t)rown * HID + ql * 32 + c * 8);
      wlds[12 + c][tid] = pack8u(Whh1 + (size_t)rown * HID + ql * 32 + c * 8);
    }
  }
  const float bA = bih1[q] + bhh1[q];
  const float bB = bih1[HID + q] + bhh1[HID + q];
  const float bC = bih1[2 * HID + q];
  const float bD = bhh1[2 * HID + q];
  const float wl = Wlin[q];
  const float blv = blin[0];

  float hprev = 0.f;
  if (tid < 64) ((float*)s1h[0])[tid] = 0.f;
  const uint4* hsrc = (const uint4*)(h1g + (size_t)b * SEQ * HID);  // 16/t
  if (tid < 16) ((uint4*)hb[0])[tid] = hsrc[tid];
  __syncthreads();

  float* outp = out + (size_t)b * SEQ;

  for (int t = 0; t < SEQ; ++t) {
    const int rb = t & 1, wb = rb ^ 1;
    const bool ldh = (ql == 2) && (q < 16);
    uint4 hn;
    if (ldh) hn = hsrc[(size_t)((t + 1 < SEQ) ? t + 1 : SEQ - 1) * 16 + q];

    const uint4* hp = (const uint4*)hb[rb];
    const uint4 h0 = hp[ql * 4], h1 = hp[ql * 4 + 1],
                h2v = hp[ql * 4 + 2], h3 = hp[ql * 4 + 3];
    const uint4* sp = (const uint4*)s1h[rb];
    const uint4 s0 = sp[ql * 4], s1 = sp[ql * 4 + 1],
                s2 = sp[ql * 4 + 2], s3 = sp[ql * 4 + 3];

    float a0 = 0.f, a0b = 0.f, a1 = 0.f, a1b = 0.f;
    float a2 = 0.f, a2b = 0.f, a3 = 0.f, a3b = 0.f;
    // r: wi1r (regs) . h  +  wh1r (LDS) . s
    DOTU4(&wi1r[0], h0, a0)  DOTU4(&wi1r[4], h1, a0)
    DOTU4(&wi1r[8], h2v, a0b) DOTU4(&wi1r[12], h3, a0b)
    {
      uint4 w0 = wlds[0][tid], w1 = wlds[1][tid], w2 = wlds[2][tid], w3 = wlds[3][tid];
      DOTW(w0, s0, a0) DOTW(w1, s1, a0) DOTW(w2, s2, a0b) DOTW(w3, s3, a0b)
    }
    // z
    DOTU4(&wi1z[0], h0, a1)  DOTU4(&wi1z[4], h1, a1)
    DOTU4(&wi1z[8], h2v, a1b) DOTU4(&wi1z[12], h3, a1b)
    {
      uint4 w0 = wlds[4][tid], w1 = wlds[5][tid], w2 = wlds[6][tid], w3 = wlds[7][tid];
      DOTW(w0, s0, a1) DOTW(w1, s1, a1) DOTW(w2, s2, a1b) DOTW(w3, s3, a1b)
    }
    // n, x-part: wi1n (LDS) . h
    {
      uint4 w0 = wlds[8][tid], w1 = wlds[9][tid], w2 = wlds[10][tid], w3 = wlds[11][tid];
      DOTW(w0, h0, a2) DOTW(w1, h1, a2) DOTW(w2, h2v, a2b) DOTW(w3, h3, a2b)
    }
    // n, h-part: wh1n (LDS) . s
    {
      uint4 w0 = wlds[12][tid], w1 = wlds[13][tid], w2 = wlds[14][tid], w3 = wlds[15][tid];
      DOTW(w0, s0, a3) DOTW(w1, s1, a3) DOTW(w2, s2, a3b) DOTW(w3, s3, a3b)
    }
    a0 += a0b; a1 += a1b; a2 += a2b; a3 += a3b;
    a0 += __shfl_xor(a0, 1, 64); a0 += __shfl_xor(a0, 2, 64);
    a1 += __shfl_xor(a1, 1, 64); a1 += __shfl_xor(a1, 2, 64);
    a2 += __shfl_xor(a2, 1, 64); a2 += __shfl_xor(a2, 2, 64);
    a3 += __shfl_xor(a3, 1, 64); a3 += __shfl_xor(a3, 2, 64);

    float p = 0.f;
    if (ql == 0) {
      float r = sigm(a0 + bA);
      float z = sigm(a1 + bB);
      float n = tanh_f(a2 + bC + r * (a3 + bD));
      float h = (1.f - z) * n + z * hprev;
      hprev = h;
      s1h[wb][q] = (_Float16)h;
      p = fmaxf(h, 0.f) * wl;
    } else if (ldh) {
      ((uint4*)hb[wb])[q] = hn;
    }
    p += __shfl_xor(p, 4, 64);
    p += __shfl_xor(p, 8, 64);
    p += __shfl_xor(p, 16, 64);
    p += __shfl_xor(p, 32, 64);
    if ((tid & 63) == 0) pw[rb][tid >> 6] = p;
    lbar();
    if (tid == 0) {
      float s = blv;
#pragma unroll
      for (int j = 0; j < 8; ++j) s += pw[rb][j];
      obuf[(t >> 4) & 1][t & 15] = s;
      if ((t & 15) == 15) {   // flush 16 outputs (64B); drains lazily
        const float4* ob = (const float4*)obuf[(t >> 4) & 1];
        float4 o0 = ob[0], o1 = ob[1], o2 = ob[2], o3 = ob[3];
        float4* dst = (float4*)(outp + (t - 15));
        dst[0] = o0; dst[1] = o1; dst[2] = o2; dst[3] = o3;
      }
    }
  }
}

extern "C" void kernel_launch(void* const* d_in, const int* in_sizes, int n_in,
                              void* d_out, int out_size, void* d_ws, size_t ws_size,
                              hipStream_t stream) {
  const float* x    = (const float*)d_in[0];
  const float* Wih0 = (const float*)d_in[1];
  const float* Whh0 = (const float*)d_in[2];
  const float* bih0 = (const float*)d_in[3];
  const float* bhh0 = (const float*)d_in[4];
  const float* Wih1 = (const float*)d_in[5];
  const float* Whh1 = (const float*)d_in[6];
  const float* bih1 = (const float*)d_in[7];
  const float* bhh1 = (const float*)d_in[8];
  const float* Wlin = (const float*)d_in[9];
  const float* blin = (const float*)d_in[10];
  float* outp = (float*)d_out;

  const int Bn = in_sizes[0] / (SEQ * INSZ);   // 256
  unsigned short* h1g = (unsigned short*)d_ws; // B*SEQ*HID f16 = 78.6 MB

  hipLaunchKernelGGL(gru_l1, dim3(Bn), dim3(512), 0, stream,
                     x, Wih0, Whh0, bih0, bhh0, h1g);
  hipLaunchKernelGGL(gru_l2, dim3(Bn), dim3(512), 0, stream,
                     h1g, Wih1, Whh1, bih1, bhh1, Wlin, blin, outp);
}

// Round 12
// 1848.008 us; speedup vs baseline: 1.3946x; 1.1337x over previous
//
#include <hip/hip_runtime.h>
#include <hip/hip_bf16.h>

// ---------------------------------------------------------------------------
// 2-layer GRU + ReLU + Linear as two sequential kernels, 256 blocks x 256 thr.
// Allocator law (R1-R11): arch-VGPR cap = 65536/blockDim; weights beyond it
// get AGPR-spilled at ~6cyc/dot2 (VALU moves), and LDS-streaming them instead
// is LDS-BW-bound (R11 K2). At 256 threads the cap is 256 regs -> BOTH layers
// fit their full weight set architecturally with a 2-way k-split:
//   K1: wi0(24)+wh0(96) = 120 h2 + ~50 working  ~= 170 regs
//   K2: wi1(96)+wh1(96) = 192 h2 + chunked state ~= 235 regs
// Per step: thread owns rows {q,128+q,256+q} (q=tid>>1), k-half ql=tid&1;
// one-round butterfly reduce; E in even lanes; state double-buffered in LDS;
// ONE light (lgkm-only) barrier per step; h1/out stores batched x16 via rings;
// K2 output reduction deferred to the every-16-step flush (off critical path).
// ---------------------------------------------------------------------------

typedef _Float16 h2 __attribute__((ext_vector_type(2)));

__device__ __forceinline__ float dot2f(h2 a, h2 b, float c) {
#if __has_builtin(__builtin_amdgcn_fdot2)
  return __builtin_amdgcn_fdot2(a, b, c, false);
#else
  return c + (float)a[0] * (float)b[0] + (float)a[1] * (float)b[1];
#endif
}
__device__ __forceinline__ h2 pack2(float x, float y) {
  h2 r; r[0] = (_Float16)x; r[1] = (_Float16)y; return r;
}
__device__ __forceinline__ float sigm(float x) { return 1.f / (1.f + __expf(-x)); }
__device__ __forceinline__ float tanh_f(float x) {
  x = fminf(fmaxf(x, -15.f), 15.f);
  float e = __expf(2.f * x);
  return (e - 1.f) / (e + 1.f);
}
__device__ __forceinline__ void load_pack8(const float* p, h2* w) {
  float4 a = ((const float4*)p)[0], b = ((const float4*)p)[1];
  w[0] = pack2(a.x, a.y); w[1] = pack2(a.z, a.w);
  w[2] = pack2(b.x, b.y); w[3] = pack2(b.z, b.w);
}
// Light barrier: waits LDS ops only (global stores keep draining lazily).
__device__ __forceinline__ void lbar() {
  asm volatile("s_waitcnt lgkmcnt(0)\ns_barrier" ::: "memory");
}

#define SEQ 1200
#define HID 128
#define INSZ 32

// 4 dot2 of a h2[4] weight group against a uint4 (8 f16) state fragment
#define DOTU4(W, U, ACC)                                            \
  ACC = dot2f((W)[0], __builtin_bit_cast(h2, (U).x), ACC);          \
  ACC = dot2f((W)[1], __builtin_bit_cast(h2, (U).y), ACC);          \
  ACC = dot2f((W)[2], __builtin_bit_cast(h2, (U).z), ACC);          \
  ACC = dot2f((W)[3], __builtin_bit_cast(h2, (U).w), ACC);

// =================== Kernel 1: layer-1 GRU, h1 -> scratch ===================
__global__ __launch_bounds__(256) void gru_l1(
    const float* __restrict__ x,
    const float* __restrict__ Wih0, const float* __restrict__ Whh0,
    const float* __restrict__ bih0, const float* __restrict__ bhh0,
    unsigned short* __restrict__ h1g)
{
  const int tid = threadIdx.x, b = blockIdx.x;
  const int q = tid >> 1, ql = tid & 1;   // unit q (0..127), k-half ql

  __shared__ __align__(16) _Float16 s0h[2][HID];        // h1 state, dbl-buf
  __shared__ __align__(16) _Float16 xh[2][INSZ];        // x row, dbl-buf
  __shared__ __align__(16) _Float16 ring[2][16][HID];   // h1 out ring (8KB)

  // per-thread weights: rows {q, 128+q, 256+q}, k-half ql. 120 h2 regs.
  h2 wi0[3][8];    // W_ih0 row k-half (16 f16)
  h2 wh0[3][32];   // W_hh0 row k-half (64 f16)
#pragma unroll
  for (int g = 0; g < 3; ++g) {
    const int row = g * HID + q;
    load_pack8(Wih0 + (size_t)row * INSZ + ql * 16,     &wi0[g][0]);
    load_pack8(Wih0 + (size_t)row * INSZ + ql * 16 + 8, &wi0[g][4]);
#pragma unroll
    for (int c = 0; c < 8; ++c)
      load_pack8(Whh0 + (size_t)row * HID + ql * 64 + c * 8, &wh0[g][c * 4]);
  }
  const float bA = bih0[q] + bhh0[q];
  const float bB = bih0[HID + q] + bhh0[HID + q];
  const float bC = bih0[2 * HID + q];
  const float bD = bhh0[2 * HID + q];

  float hprev = 0.f;
  if (tid < 64) ((float*)s0h[0])[tid] = 0.f;
  const float2* xsrc = (const float2*)x + (size_t)b * SEQ * (INSZ / 2);
  if (tid < 16) { float2 v = xsrc[tid]; ((h2*)xh[0])[tid] = pack2(v.x, v.y); }
  __syncthreads();

  unsigned short* hout = h1g + (size_t)b * SEQ * HID;

  for (int t = 0; t < SEQ; ++t) {
    const int rb = t & 1, wb = rb ^ 1;
    // prefetch x_{t+1} on wave-1 odd lanes (no overlap with E lanes' work)
    const bool ldx = (ql == 1) && (q >= 32) && (q < 48);
    float2 xn;
    if (ldx) xn = xsrc[(size_t)((t + 1 < SEQ) ? t + 1 : SEQ - 1) * 16 + (q - 32)];

    const uint4* xp = (const uint4*)xh[rb];
    const uint4* sp = (const uint4*)s0h[rb];
    float a0 = 0.f, a1 = 0.f, a2 = 0.f, a3 = 0.f;
    {  // x-part (16 f16 = 2 chunks)
      const uint4 x0 = xp[ql * 2], x1 = xp[ql * 2 + 1];
      DOTU4(&wi0[0][0], x0, a0) DOTU4(&wi0[0][4], x1, a0)
      DOTU4(&wi0[1][0], x0, a1) DOTU4(&wi0[1][4], x1, a1)
      DOTU4(&wi0[2][0], x0, a2) DOTU4(&wi0[2][4], x1, a2)
    }
#pragma unroll
    for (int c = 0; c < 8; ++c) {  // h-part, chunked (keeps live state small)
      const uint4 s = sp[ql * 8 + c];
      DOTU4(&wh0[0][c * 4], s, a0)
      DOTU4(&wh0[1][c * 4], s, a1)
      DOTU4(&wh0[2][c * 4], s, a3)
    }
    a0 += __shfl_xor(a0, 1, 64);
    a1 += __shfl_xor(a1, 1, 64);
    a2 += __shfl_xor(a2, 1, 64);
    a3 += __shfl_xor(a3, 1, 64);

    if (ql == 0) {
      float r = sigm(a0 + bA);
      float z = sigm(a1 + bB);
      float n = tanh_f(a2 + bC + r * (a3 + bD));
      float h = (1.f - z) * n + z * hprev;
      hprev = h;
      const _Float16 hf = (_Float16)h;
      s0h[wb][q] = hf;
      ring[(t >> 4) & 1][t & 15][q] = hf;
    } else if (ldx) {
      ((h2*)xh[wb])[q - 32] = pack2(xn.x, xn.y);
    }
    lbar();
    if ((t & 15) == 15) {   // flush 16 rows (4KB) coalesced; drains lazily
      const uint4 v = ((const uint4*)ring[(t >> 4) & 1])[tid];
      ((uint4*)(hout + (size_t)(t - 15) * HID))[tid] = v;
    }
  }
}

// ============ Kernel 2: layer-2 GRU + ReLU + Linear head -> out ============
__global__ __launch_bounds__(256) void gru_l2(
    const unsigned short* __restrict__ h1g,
    const float* __restrict__ Wih1, const float* __restrict__ Whh1,
    const float* __restrict__ bih1, const float* __restrict__ bhh1,
    const float* __restrict__ Wlin, const float* __restrict__ blin,
    float* __restrict__ out)
{
  const int tid = threadIdx.x, b = blockIdx.x;
  const int q = tid >> 1, ql = tid & 1;

  __shared__ __align__(16) _Float16 s1h[2][HID];   // h2 state, dbl-buf
  __shared__ __align__(16) _Float16 hb[2][HID];    // staged h1_t, dbl-buf
  __shared__ float pring[2][16][HID];              // ReLU(h)*w partials (16KB)

  // per-thread weights: rows {q, 128+q, 256+q}, k-half ql. 192 h2 regs.
  h2 wi1[3][32];   // W_ih1 row k-half (64 f16)
  h2 wh1[3][32];   // W_hh1 row k-half
#pragma unroll
  for (int g = 0; g < 3; ++g) {
    const int row = g * HID + q;
#pragma unroll
    for (int c = 0; c < 8; ++c) {
      load_pack8(Wih1 + (size_t)row * HID + ql * 64 + c * 8, &wi1[g][c * 4]);
      load_pack8(Whh1 + (size_t)row * HID + ql * 64 + c * 8, &wh1[g][c * 4]);
    }
  }
  const float bA = bih1[q] + bhh1[q];
  const float bB = bih1[HID + q] + bhh1[HID + q];
  const float bC = bih1[2 * HID + q];
  const float bD = bhh1[2 * HID + q];
  const float wl = Wlin[q];
  const float blv = blin[0];

  float hprev = 0.f;
  if (tid < 64) ((float*)s1h[0])[tid] = 0.f;
  const uint4* hsrc = (const uint4*)(h1g + (size_t)b * SEQ * HID);  // 16 / t
  if (tid < 16) ((uint4*)hb[0])[tid] = hsrc[tid];
  __syncthreads();

  float* outp = out + (size_t)b * SEQ;

  for (int t = 0; t < SEQ; ++t) {
    const int rb = t & 1, wb = rb ^ 1;
    // prefetch h1_{t+1} on wave-1 odd lanes
    const bool ldh = (ql == 1) && (q >= 32) && (q < 48);
    uint4 hn;
    if (ldh) hn = hsrc[(size_t)((t + 1 < SEQ) ? t + 1 : SEQ - 1) * 16 + (q - 32)];

    const uint4* hp = (const uint4*)hb[rb];
    const uint4* sp = (const uint4*)s1h[rb];
    float a0 = 0.f, a1 = 0.f, a2 = 0.f, a3 = 0.f;
#pragma unroll
    for (int c = 0; c < 8; ++c) {  // chunked: 2 live state uint4 at a time
      const uint4 hu = hp[ql * 8 + c];
      const uint4 su = sp[ql * 8 + c];
      DOTU4(&wi1[0][c * 4], hu, a0) DOTU4(&wh1[0][c * 4], su, a0)
      DOTU4(&wi1[1][c * 4], hu, a1) DOTU4(&wh1[1][c * 4], su, a1)
      DOTU4(&wi1[2][c * 4], hu, a2) DOTU4(&wh1[2][c * 4], su, a3)
    }
    a0 += __shfl_xor(a0, 1, 64);
    a1 += __shfl_xor(a1, 1, 64);
    a2 += __shfl_xor(a2, 1, 64);
    a3 += __shfl_xor(a3, 1, 64);

    if (ql == 0) {
      float r = sigm(a0 + bA);
      float z = sigm(a1 + bB);
      float n = tanh_f(a2 + bC + r * (a3 + bD));
      float h = (1.f - z) * n + z * hprev;
      hprev = h;
      s1h[wb][q] = (_Float16)h;
      pring[(t >> 4) & 1][t & 15][q] = fmaxf(h, 0.f) * wl;   // deferred reduce
    } else if (ldh) {
      ((uint4*)hb[wb])[q - 32] = hn;
    }
    lbar();
    if ((t & 15) == 15 && tid < 64) {   // flush: 16 outputs, wave 0 only
      const int o = tid >> 2, qp = tid & 3;
      const float* pr = &pring[(t >> 4) & 1][o][qp * 32];
      float s0 = 0.f, s1 = 0.f;
#pragma unroll
      for (int j = 0; j < 16; ++j) {    // lane-staggered: conflict-free banks
        s0 += pr[(2 * j + tid) & 31];
        s1 += pr[(2 * j + 1 + tid) & 31];
      }
      float s = s0 + s1;
      s += __shfl_xor(s, 1, 64);
      s += __shfl_xor(s, 2, 64);
      if (qp == 0) outp[t - 15 + o] = s + blv;
    }
  }
}

extern "C" void kernel_launch(void* const* d_in, const int* in_sizes, int n_in,
                              void* d_out, int out_size, void* d_ws, size_t ws_size,
                              hipStream_t stream) {
  const float* x    = (const float*)d_in[0];
  const float* Wih0 = (const float*)d_in[1];
  const float* Whh0 = (const float*)d_in[2];
  const float* bih0 = (const float*)d_in[3];
  const float* bhh0 = (const float*)d_in[4];
  const float* Wih1 = (const float*)d_in[5];
  const float* Whh1 = (const float*)d_in[6];
  const float* bih1 = (const float*)d_in[7];
  const float* bhh1 = (const float*)d_in[8];
  const float* Wlin = (const float*)d_in[9];
  const float* blin = (const float*)d_in[10];
  float* outp = (float*)d_out;

  const int Bn = in_sizes[0] / (SEQ * INSZ);   // 256
  unsigned short* h1g = (unsigned short*)d_ws; // B*SEQ*HID f16 = 78.6 MB

  hipLaunchKernelGGL(gru_l1, dim3(Bn), dim3(256), 0, stream,
                     x, Wih0, Whh0, bih0, bhh0, h1g);
  hipLaunchKernelGGL(gru_l2, dim3(Bn), dim3(256), 0, stream,
                     h1g, Wih1, Whh1, bih1, bhh1, Wlin, blin, outp);
}